// Round 16
// baseline (157.521 us; speedup 1.0000x reference)
//
#include <hip/hip_runtime.h>
#include <hip/hip_bf16.h>
#include <stdint.h>

// Problem constants
#define NT 4096      // tokens
#define DM 320       // model dim
#define NH 8         // heads
#define DH 40        // head dim
#define KS 8         // split-K factor (oversubscription -> dynamic load balance)
#define QSCALE 0.22811013f  // (1/sqrt(40)) * log2(e): folded into Q so p = exp2(qk)
#define PSTR 68      // P-tile LDS row stride (ushorts): b64 8B-aligned, <=2-way banks
#define KFJB 640     // Kf shorts per 16-key block: 512 (k<32) + 128 (k=32..39, quad0)

typedef float f32x4 __attribute__((ext_vector_type(4)));
typedef __bf16 bf16x8 __attribute__((ext_vector_type(8)));

__device__ __forceinline__ unsigned short f2b(float f) {
  unsigned u = __builtin_bit_cast(unsigned, f);
  u += 0x7FFFu + ((u >> 16) & 1u);   // RNE
  return (unsigned short)(u >> 16);
}

__device__ __forceinline__ bf16x8 ld_bf8(const unsigned short* p) {
  uint4 v = *(const uint4*)p;        // 16B load
  return __builtin_bit_cast(bf16x8, v);
}

__device__ __forceinline__ f32x4 mfma16(bf16x8 a, bf16x8 b, f32x4 c) {
  return __builtin_amdgcn_mfma_f32_16x16x32_bf16(a, b, c, 0, 0, 0);
}

__device__ __forceinline__ float fexp2(float x) {
#if __has_builtin(__builtin_amdgcn_exp2f)
  return __builtin_amdgcn_exp2f(x);
#else
  float r; asm("v_exp_f32 %0, %1" : "=v"(r) : "v"(x)); return r;
#endif
}

__device__ __forceinline__ uint2 pack4(float a, float b, float c, float d) {
  uint2 pk;
  pk.x = (unsigned)f2b(a) | ((unsigned)f2b(b) << 16);
  pk.y = (unsigned)f2b(c) | ((unsigned)f2b(d) << 16);
  return pk;
}

// Fragment-major index: element (outer o in 16-tile `tile`, inner k of nk 32-tiles)
__device__ __forceinline__ size_t fmi(int tile, int nk, int k, int o) {
  return ((size_t)tile * nk + (k >> 5)) * 512 + (size_t)((k >> 3) & 3) * 128 +
         (size_t)(o & 15) * 8 + (k & 7);
}

// ---------------- kernel 1: fused QKV projection + sig/partition ----------------
// grid (64,16). cy 0..14: GEMM (a=cy/5: Q/K/V; cc0=cy%5*64) with W read scattered
// fp32 straight from global + inline f2b (no LDS, no barrier — avoids r13's trap);
// x fp32 inline. cy==15,bx==0: signatures + stable partition (sig!=0 first).
// Q: row layout Qb[h][m][64] (d<40). K/V: frag-major for attn's 1KB wave loads.
__global__ __launch_bounds__(256, 4) void qkv_gemm(
    const float* __restrict__ x, const float* __restrict__ g,
    const float* __restrict__ Wq, const float* __restrict__ Wk,
    const float* __restrict__ Wv,
    unsigned char* __restrict__ sigb, int* __restrict__ perm,
    int* __restrict__ nqp, unsigned short* __restrict__ Qb,
    unsigned short* __restrict__ Kf, unsigned short* __restrict__ Vf) {
  const int t = threadIdx.x;
  const int cy = blockIdx.y;
  if (cy == 15) {                       // ---- signatures + partition
    if (blockIdx.x != 0) return;
    __shared__ int cnt[256];
    unsigned char mys[16];
    int c1 = 0;
#pragma unroll
    for (int i = 0; i < 16; ++i) {
      int tok = t * 16 + i;
      unsigned s = 0;
      if (g[tok] != 0.f)          s |= 1u;
      if (g[NT + tok] != 0.f)     s |= 2u;
      if (g[2 * NT + tok] != 0.f) s |= 4u;
      sigb[tok] = (unsigned char)s;
      mys[i] = (unsigned char)s;
      c1 += (s != 0u);
    }
    cnt[t] = c1;
    __syncthreads();
    for (int off = 1; off < 256; off <<= 1) {   // inclusive scan
      int v = (t >= off) ? cnt[t - off] : 0;
      __syncthreads();
      cnt[t] += v;
      __syncthreads();
    }
    const int nq = cnt[255];
    int p1 = cnt[t] - c1;                       // exclusive prefix of non-zero
    int p0 = nq + (t * 16 - p1);                // sig0 slots after all non-zero
#pragma unroll
    for (int i = 0; i < 16; ++i) {
      int tok = t * 16 + i;
      if (mys[i] != 0) perm[p1++] = tok;
      else             perm[p0++] = tok;
    }
    if (t == 0) nqp[0] = nq;
    return;
  }
  const int w = t >> 6, lane = t & 63, quad = lane >> 4, ln = lane & 15;
  const int m0 = blockIdx.x * 64;
  const int a = cy / 5;                       // 0=Q 1=K 2=V
  const int cc0 = (cy % 5) * 64;
  const float* Wsrc = (a == 0) ? Wq : ((a == 1) ? Wk : Wv);
  const float* xrow = x + (size_t)(m0 + w * 16 + ln) * DM + quad * 8;

  f32x4 acc[4] = {{0,0,0,0},{0,0,0,0},{0,0,0,0},{0,0,0,0}};
  for (int kc = 0; kc < 10; ++kc) {
    float4 a0 = *(const float4*)(xrow + kc * 32);
    float4 a1 = *(const float4*)(xrow + kc * 32 + 4);
    unsigned short x8[8];
    x8[0] = f2b(a0.x); x8[1] = f2b(a0.y); x8[2] = f2b(a0.z); x8[3] = f2b(a0.w);
    x8[4] = f2b(a1.x); x8[5] = f2b(a1.y); x8[6] = f2b(a1.z); x8[7] = f2b(a1.w);
    bf16x8 xf = ld_bf8(x8);
    const float* Wk0 = Wsrc + (size_t)(kc * 32 + quad * 8) * DM + cc0 + ln;
#pragma unroll
    for (int nt = 0; nt < 4; ++nt) {
      const float* wp = Wk0 + nt * 16;
      unsigned short w8[8];
#pragma unroll
      for (int e = 0; e < 8; ++e) w8[e] = f2b(wp[(size_t)e * DM]);
      bf16x8 wf = ld_bf8(w8);
      if (a < 2) acc[nt] = mfma16(wf, xf, acc[nt]);   // D[c=quad*4+r][m=ln]
      else       acc[nt] = mfma16(xf, wf, acc[nt]);   // D[m=quad*4+r][c=ln]
    }
  }
  if (a == 0) {
    const int m = m0 + w * 16 + ln;
#pragma unroll
    for (int nt = 0; nt < 4; ++nt) {
      int c = cc0 + nt * 16 + quad * 4;       // 4 consecutive d, no h-crossing
      int h = c / DH, d = c % DH;
      uint2 pk = pack4(acc[nt][0] * QSCALE, acc[nt][1] * QSCALE,
                       acc[nt][2] * QSCALE, acc[nt][3] * QSCALE);
      *(uint2*)&Qb[((size_t)h * NT + m) * 64 + d] = pk;
    }
  } else if (a == 1) {
    const int m = m0 + w * 16 + ln;
#pragma unroll
    for (int nt = 0; nt < 4; ++nt) {
      int c = cc0 + nt * 16 + quad * 4;
      int h = c / DH, d = c % DH;
      uint2 pk = pack4(acc[nt][0], acc[nt][1], acc[nt][2], acc[nt][3]);
      size_t base = ((size_t)h * 256 + (m >> 4)) * KFJB;
      size_t idx = (d < 32)
          ? base + (size_t)(d >> 3) * 128 + (size_t)(m & 15) * 8 + (d & 7)
          : base + 512 + (size_t)(m & 15) * 8 + (d - 32);
      *(uint2*)&Kf[idx] = pk;
    }
  } else {
    const int mb = m0 + w * 16 + quad * 4;    // 4 consecutive m
#pragma unroll
    for (int nt = 0; nt < 4; ++nt) {
      int c = cc0 + nt * 16 + ln;
      int h = c / DH, d = c % DH;
      uint2 pk = pack4(acc[nt][0], acc[nt][1], acc[nt][2], acc[nt][3]);
      size_t idx = ((((((size_t)(h * 64 + (mb >> 6)) * 3 + (d >> 4)) * 2 +
                       ((mb >> 5) & 1)) * 4 + ((mb >> 3) & 3)) * 16 + (d & 15))) * 8 +
                   (mb & 7);
      *(uint2*)&Vf[idx] = pk;
    }
  }
}

// ---------------- kernel 2: partitioned masked attention (KS=8) ----------------
// grid (32,8,8) = 2048 blocks = 2x CU capacity: the dispatch queue refills CUs as
// cheap writer blocks retire -> dynamic load balance (r15's 4/CU static mapping
// put 4 same-type blocks on each CU and erased the partition win).
__global__ __launch_bounds__(256, 4) void attn_kernel(
    const unsigned short* __restrict__ Qb, const unsigned short* __restrict__ Kf,
    const unsigned short* __restrict__ Vf, const unsigned char* __restrict__ sigb,
    const int* __restrict__ perm, const int* __restrict__ nqp,
    unsigned short* __restrict__ Opf, float* __restrict__ Lpart) {
  __shared__ __align__(16) unsigned short pt[4][32 * PSTR];   // per-wave P^T 17408 B
  const int t = threadIdx.x;
  const int w = t >> 6, lane = t & 63, quad = lane >> 4, ln = lane & 15;
  const int h = blockIdx.y, qt = blockIdx.x, sp = blockIdx.z;
  const int qrow = qt * 128 + w * 32;
  const int j0 = sp * 8;
  const int nq_pad = (nqp[0] + 127) & ~127;
  const bool writer = (qt * 128 >= nq_pad);   // block-uniform

  const unsigned short* Kfh = Kf + (size_t)h * 256 * KFJB;
  const unsigned short* Vfh = Vf + (size_t)h * 196608;   // 64jt * 3ot * 2c * 512
  unsigned short* ptw = pt[w];
  const uint4 z4 = {0, 0, 0, 0};
  const uint4 ones4 = {0x3F803F80u, 0x3F803F80u, 0x3F803F80u, 0x3F803F80u};
  const bf16x8 onesb = __builtin_bit_cast(bf16x8, ones4);
  const bool vone = (ln == 8);             // d=40 rows of the ot=2 V-frag -> 1.0

  bf16x8 qa[2][2];
  unsigned sqx4[2], uqx4[2];
  int morig[2];
  f32x4 o[3][2] = {{{0,0,0,0},{0,0,0,0}},{{0,0,0,0},{0,0,0,0}},{{0,0,0,0},{0,0,0,0}}};

#pragma unroll
  for (int tq = 0; tq < 2; ++tq) {
    int bp = qrow + tq * 16 + ln;
    int mo = perm[bp];
    morig[tq] = mo;
    if (!writer) {
      const unsigned short* Qp = Qb + ((size_t)h * NT + mo) * 64;
      qa[tq][0] = ld_bf8(Qp + quad * 8);                // k 0..31
      uint4 q1 = z4;                                    // k 32..39: quad0 real
      if (quad == 0) q1 = *(const uint4*)(Qp + 32);
      qa[tq][1] = __builtin_bit_cast(bf16x8, q1);
      unsigned s = sigb[mo];
      sqx4[tq] = s * 0x01010101u;
      uqx4[tq] = (s == 0u) ? 0xFFFFFFFFu : 0u;
      if (s == 0u) {               // boundary pad rows: logits 0 -> p = 1
        qa[tq][0] = __builtin_bit_cast(bf16x8, z4);
        qa[tq][1] = __builtin_bit_cast(bf16x8, z4);
      }
    }
  }

  for (int jt = j0; jt < j0 + 8; ++jt) {
    if (!writer) {
      // K fragments from compact Kf: 4 x 1KB + 4 x 256B (quad0) coalesced loads
      uint4 kfr0[4], kfr1[4];
#pragma unroll
      for (int nt = 0; nt < 4; ++nt) {
        const unsigned short* kb = Kfh + (size_t)(jt * 4 + nt) * KFJB;
        kfr0[nt] = *(const uint4*)(kb + lane * 8);
        kfr1[nt] = z4;
        if (lane < 16) kfr1[nt] = *(const uint4*)(kb + 512 + lane * 8);
      }
#pragma unroll
      for (int nt = 0; nt < 4; ++nt) {
        bf16x8 ka0 = __builtin_bit_cast(bf16x8, kfr0[nt]);
        bf16x8 ka1 = __builtin_bit_cast(bf16x8, kfr1[nt]);
        unsigned spj = *(const unsigned*)(sigb + jt * 64 + nt * 16 + quad * 4);
#pragma unroll
        for (int tq = 0; tq < 2; ++tq) {
          f32x4 acc = {0.f, 0.f, 0.f, 0.f};
          acc = mfma16(ka0, qa[tq][0], acc);    // S^T[j=nt*16+quad*4+r][m=ln]
          acc = mfma16(ka1, qa[tq][1], acc);
          unsigned m4 = (spj & sqx4[tq]) | uqx4[tq];   // byte r != 0 <=> unmasked
          unsigned u[4];
#pragma unroll
          for (int r = 0; r < 4; ++r) {
            unsigned mb = (m4 >> (8 * r)) & 255u;      // v_bfe
            float am = mb ? acc[r] : -3.0e38f;         // masked -> exp2 = 0
            u[r] = __builtin_bit_cast(unsigned, fexp2(am));
          }
          uint2 pk;                                    // truncate-to-bf16 pack
          pk.x = (u[0] >> 16) | (u[1] & 0xffff0000u);  // (j+0, j+1)
          pk.y = (u[2] >> 16) | (u[3] & 0xffff0000u);  // (j+2, j+3)
          *(uint2*)&ptw[(tq * 16 + ln) * PSTR + nt * 16 + quad * 4] = pk;  // b64
        }
      }
    }
    // V fragments (6 coalesced 1KB wave loads); ones-column d=40 in-register
    uint4 vfr[6];
#pragma unroll
    for (int ot = 0; ot < 3; ++ot)
#pragma unroll
      for (int c = 0; c < 2; ++c)
        vfr[ot * 2 + c] =
            *(const uint4*)(Vfh + ((size_t)((jt * 3 + ot) * 2 + c)) * 512 + lane * 8);
    if (vone) { vfr[4] = ones4; vfr[5] = ones4; }

    bf16x8 pb[2][2];
    if (!writer) {
      asm volatile("s_waitcnt lgkmcnt(0)" ::: "memory");   // wave-private P RAW
#pragma unroll
      for (int tq = 0; tq < 2; ++tq) {
        pb[tq][0] = ld_bf8(&ptw[(tq * 16 + ln) * PSTR + quad * 8]);
        pb[tq][1] = ld_bf8(&ptw[(tq * 16 + ln) * PSTR + 32 + quad * 8]);
      }
    } else {
      pb[0][0] = onesb; pb[0][1] = onesb; pb[1][0] = onesb; pb[1][1] = onesb;
    }
#pragma unroll
    for (int ot = 0; ot < 3; ++ot) {
      bf16x8 va0 = __builtin_bit_cast(bf16x8, vfr[ot * 2]);
      bf16x8 va1 = __builtin_bit_cast(bf16x8, vfr[ot * 2 + 1]);
#pragma unroll
      for (int tq = 0; tq < 2; ++tq) {
        o[ot][tq] = mfma16(va0, pb[tq][0], o[ot][tq]);   // O^T[d][m]
        o[ot][tq] = mfma16(va1, pb[tq][1], o[ot][tq]);
      }
    }
  }

  // epilogue: O^T d = ot*16+quad*4+r; scatter by original row; d=40 -> denominator
#pragma unroll
  for (int tq = 0; tq < 2; ++tq) {
    int m = morig[tq];
#pragma unroll
    for (int ot = 0; ot < 3; ++ot) {
      int d0 = ot * 16 + quad * 4;
      if (d0 < DH) {
        int c = h * DH + d0;                  // 4 consecutive c, no 8-crossing
        uint2 pk = pack4(o[ot][tq][0], o[ot][tq][1], o[ot][tq][2], o[ot][tq][3]);
        *(uint2*)&Opf[fmi(sp * 256 + (m >> 4), 10, c, m)] = pk;
      }
    }
    if (quad == 2)
      Lpart[sp * NT + m] = o[2][tq][0];       // MFMA-computed denominator
  }
}

// ---------------- kernel 3: out projection + split-K combine + bias ----------------
// Wo read scattered fp32 from global (same lean pattern as qkv); D[c][m] via
// mfma(Wo, A): float4 out stores + float4 bias loads.
__global__ __launch_bounds__(256, 4) void out_gemm(
    const unsigned short* __restrict__ Opf, const float* __restrict__ Lpart,
    const float* __restrict__ Wo, const float* __restrict__ bo,
    float* __restrict__ out) {
  const int t = threadIdx.x;
  const int w = t >> 6, lane = t & 63, quad = lane >> 4, ln = lane & 15;
  const int m0 = blockIdx.x * 64;
  const int cc0 = blockIdx.y * 64;
  const int mt = (m0 >> 4) + w;
  const int m = m0 + w * 16 + ln;
  float ls = 0.f;
#pragma unroll
  for (int sp = 0; sp < KS; ++sp) ls += Lpart[sp * NT + m];
  const float inv = 1.f / ls;

  f32x4 acc[4] = {{0,0,0,0},{0,0,0,0},{0,0,0,0},{0,0,0,0}};
  for (int kc = 0; kc < 10; ++kc) {
    float s8[8] = {0, 0, 0, 0, 0, 0, 0, 0};
#pragma unroll
    for (int sp = 0; sp < KS; ++sp) {
      uint4 v = *(const uint4*)(Opf + ((size_t)((sp * 256 + mt) * 10 + kc)) * 512 +
                                lane * 8);
      unsigned vv[4] = {v.x, v.y, v.z, v.w};
#pragma unroll
      for (int j = 0; j < 4; ++j) {
        s8[2 * j]     += __builtin_bit_cast(float, vv[j] << 16);
        s8[2 * j + 1] += __builtin_bit_cast(float, vv[j] & 0xffff0000u);
      }
    }
    unsigned short af8[8];
#pragma unroll
    for (int j = 0; j < 8; ++j) af8[j] = f2b(s8[j] * inv);
    bf16x8 af = ld_bf8(af8);
    const float* Wk0 = Wo + (size_t)(kc * 32 + quad * 8) * DM + cc0 + ln;
#pragma unroll
    for (int nt = 0; nt < 4; ++nt) {
      const float* wp = Wk0 + nt * 16;
      unsigned short w8[8];
#pragma unroll
      for (int e = 0; e < 8; ++e) w8[e] = f2b(wp[(size_t)e * DM]);
      bf16x8 wf = ld_bf8(w8);
      acc[nt] = mfma16(wf, af, acc[nt]);      // D[c=quad*4+r][m=ln]
    }
  }
#pragma unroll
  for (int nt = 0; nt < 4; ++nt) {
    int c = cc0 + nt * 16 + quad * 4;
    float4 bv = *(const float4*)(bo + c);
    float4 ov;
    ov.x = acc[nt][0] + bv.x;
    ov.y = acc[nt][1] + bv.y;
    ov.z = acc[nt][2] + bv.z;
    ov.w = acc[nt][3] + bv.w;
    *(float4*)(out + (size_t)m * DM + c) = ov;
  }
}

// ---------------- launcher ----------------
extern "C" void kernel_launch(void* const* d_in, const int* in_sizes, int n_in,
                              void* d_out, int out_size, void* d_ws, size_t ws_size,
                              hipStream_t stream) {
  const float* x  = (const float*)d_in[0];
  const float* g  = (const float*)d_in[1];
  const float* Wq = (const float*)d_in[2];
  const float* Wk = (const float*)d_in[3];
  const float* Wv = (const float*)d_in[4];
  const float* Wo = (const float*)d_in[5];
  const float* bo = (const float*)d_in[6];
  float* out = (float*)d_out;

  char* ws = (char*)d_ws;
  const size_t SIG_OFF  = 0;                                        // 4 KB
  const size_t NQ_OFF   = 4096;                                     // 16 B
  const size_t PERM_OFF = 8192;                                     // 16 KB
  const size_t QB_OFF   = 32768;
  const size_t KF_OFF  = QB_OFF + (size_t)NH * NT * 64 * 2;         // +4.19 MB
  const size_t VF_OFF  = KF_OFF + (size_t)NH * 256 * KFJB * 2;      // +2.62 MB
  const size_t OPF_OFF = VF_OFF + (size_t)NH * 196608 * 2;          // +3.15 MB
  const size_t LP_OFF  = OPF_OFF + (size_t)KS * 256 * 10 * 512 * 2; // +20.97 MB
  unsigned char* sigb  = (unsigned char*)(ws + SIG_OFF);
  int* nqp             = (int*)(ws + NQ_OFF);
  int* perm            = (int*)(ws + PERM_OFF);
  unsigned short* Qb   = (unsigned short*)(ws + QB_OFF);
  unsigned short* Kf   = (unsigned short*)(ws + KF_OFF);
  unsigned short* Vf   = (unsigned short*)(ws + VF_OFF);
  unsigned short* Opf  = (unsigned short*)(ws + OPF_OFF);
  float* Lpart         = (float*)(ws + LP_OFF);

  // No memset: Qb k40..63 garbage never read (quad-select); Vf d=40 ones
  // in-register; Vf d=41..47 garbage feeds only discarded lanes (no NaN).
  qkv_gemm<<<dim3(64, 16), 256, 0, stream>>>(x, g, Wq, Wk, Wv, sigb, perm, nqp,
                                             Qb, Kf, Vf);
  attn_kernel<<<dim3(32, NH, KS), 256, 0, stream>>>(Qb, Kf, Vf, sigb, perm, nqp,
                                                    Opf, Lpart);
  out_gemm<<<dim3(64, 5), 256, 0, stream>>>(Opf, Lpart, Wo, bo, out);
}

// Round 17
// 140.392 us; speedup vs baseline: 1.1220x; 1.1220x over previous
//
#include <hip/hip_runtime.h>
#include <hip/hip_bf16.h>
#include <stdint.h>

// Problem constants
#define NT 4096      // tokens
#define DM 320       // model dim
#define NH 8         // heads
#define DH 40        // head dim
#define KS 4         // split-K factor over the key dimension
#define QSCALE 0.22811013f  // (1/sqrt(40)) * log2(e): folded into Q so p = exp2(qk)
#define PSTR 68      // P-tile LDS row stride (ushorts): b64 8B-aligned, <=2-way banks
#define KFJB 640     // Kf shorts per 16-key block: 512 (k<32) + 128 (k=32..39, quad0)

typedef float f32x4 __attribute__((ext_vector_type(4)));
typedef __bf16 bf16x8 __attribute__((ext_vector_type(8)));

__device__ __forceinline__ unsigned short f2b(float f) {
  unsigned u = __builtin_bit_cast(unsigned, f);
  u += 0x7FFFu + ((u >> 16) & 1u);   // RNE
  return (unsigned short)(u >> 16);
}

__device__ __forceinline__ bf16x8 ld_bf8(const unsigned short* p) {
  uint4 v = *(const uint4*)p;        // 16B load
  return __builtin_bit_cast(bf16x8, v);
}

__device__ __forceinline__ f32x4 mfma16(bf16x8 a, bf16x8 b, f32x4 c) {
  return __builtin_amdgcn_mfma_f32_16x16x32_bf16(a, b, c, 0, 0, 0);
}

__device__ __forceinline__ float fexp2(float x) {
#if __has_builtin(__builtin_amdgcn_exp2f)
  return __builtin_amdgcn_exp2f(x);
#else
  float r; asm("v_exp_f32 %0, %1" : "=v"(r) : "v"(x)); return r;
#endif
}

__device__ __forceinline__ uint2 pack4(float a, float b, float c, float d) {
  uint2 pk;
  pk.x = (unsigned)f2b(a) | ((unsigned)f2b(b) << 16);
  pk.y = (unsigned)f2b(c) | ((unsigned)f2b(d) << 16);
  return pk;
}

// Fragment-major index: element (outer o in 16-tile `tile`, inner k of nk 32-tiles)
__device__ __forceinline__ size_t fmi(int tile, int nk, int k, int o) {
  return ((size_t)tile * nk + (k >> 5)) * 512 + (size_t)((k >> 3) & 3) * 128 +
         (size_t)(o & 15) * 8 + (k & 7);
}

// ---------------- kernel 1: prep (weights->Wtf | sig+partition | x->xbf) ---------
__global__ __launch_bounds__(256) void prep_kernel(
    const float* __restrict__ x, const float* __restrict__ g,
    const float* __restrict__ Wq, const float* __restrict__ Wk,
    const float* __restrict__ Wv, const float* __restrict__ Wo,
    unsigned short* __restrict__ xbf, unsigned char* __restrict__ sigb,
    unsigned short* __restrict__ Wtf, int* __restrict__ perm,
    int* __restrict__ nqp) {
  const int b = blockIdx.x, t = threadIdx.x;
  if (b == 100) {                       // ---- signatures + partition
    __shared__ int cnt[256];
    unsigned char mys[16];
    int c1 = 0;
#pragma unroll
    for (int i = 0; i < 16; ++i) {
      int tok = t * 16 + i;
      unsigned s = 0;
      if (g[tok] != 0.f)          s |= 1u;
      if (g[NT + tok] != 0.f)     s |= 2u;
      if (g[2 * NT + tok] != 0.f) s |= 4u;
      sigb[tok] = (unsigned char)s;
      mys[i] = (unsigned char)s;
      c1 += (s != 0u);
    }
    cnt[t] = c1;
    __syncthreads();
    for (int off = 1; off < 256; off <<= 1) {   // inclusive scan
      int v = (t >= off) ? cnt[t - off] : 0;
      __syncthreads();
      cnt[t] += v;
      __syncthreads();
    }
    const int nq = cnt[255];
    int p1 = cnt[t] - c1;                       // exclusive prefix of non-zero
    int p0 = nq + (t * 16 - p1);                // sig0 slots after all non-zero
#pragma unroll
    for (int i = 0; i < 16; ++i) {
      int tok = t * 16 + i;
      if (mys[i] != 0) perm[p1++] = tok;
      else             perm[p0++] = tok;
    }
    if (t == 0) nqp[0] = nq;
    return;
  }
  if (b > 100) {                        // ---- x -> bf16 frag-major (fat blocks)
    int base = (b - 101) * 2560;        // 128 blocks x 2560 float4
#pragma unroll
    for (int j = 0; j < 10; ++j) {
      int i = (base + j * 256 + t) * 4;
      int m = i / DM, k = i % DM;
      float4 v = *(const float4*)(x + i);
      ushort4 u;
      u.x = f2b(v.x); u.y = f2b(v.y); u.z = f2b(v.z); u.w = f2b(v.w);
      *(ushort4*)(xbf + fmi(m >> 4, 10, k, m)) = u;
    }
    return;
  }
  // ---- weights -> bf16 transposed frag-major
  __shared__ __align__(16) unsigned short lt[64 * 72];
  int kx = b % 5, cy = b / 5;           // kx: k-tile, cy: c-tile over 4 mats
  int cm = cy % 5;
  const float* src;
  int rowbase;
  if (cy < 5)       { src = Wq; rowbase = cm * 64; }
  else if (cy < 10) { src = Wk; rowbase = 320 + cm * 64; }
  else if (cy < 15) { src = Wv; rowbase = 640 + cm * 64; }
  else              { src = Wo; rowbase = 960 + cm * 64; }
  const int c0 = cm * 64;
  const int k0 = kx * 64;
#pragma unroll
  for (int i = 0; i < 4; ++i) {         // read 64k x 64c fp32, transpose to LDS
    int kr = (t >> 4) + i * 16, cc = (t & 15) * 4;
    float4 w4 = *(const float4*)&src[(size_t)(k0 + kr) * DM + c0 + cc];
    lt[(cc + 0) * 72 + kr] = f2b(w4.x);
    lt[(cc + 1) * 72 + kr] = f2b(w4.y);
    lt[(cc + 2) * 72 + kr] = f2b(w4.z);
    lt[(cc + 3) * 72 + kr] = f2b(w4.w);
  }
  __syncthreads();
#pragma unroll
  for (int i = 0; i < 2; ++i) {         // scatter to frag-major (8-short chunks)
    int idx = t + i * 256, cl = idx >> 3, ch = idx & 7;
    int c = rowbase + cl, k = k0 + ch * 8;
    *(uint4*)&Wtf[fmi(c >> 4, 10, k, c)] = *(const uint4*)&lt[cl * 72 + ch * 8];
  }
}

// ---------------- kernel 2: fused QKV projection (frag-major in) ----------------
__global__ __launch_bounds__(256, 4) void qkv_gemm(
    const unsigned short* __restrict__ xbf, const unsigned short* __restrict__ Wtf,
    unsigned short* __restrict__ Qb, unsigned short* __restrict__ Kf,
    unsigned short* __restrict__ Vf) {
  const int t = threadIdx.x;
  const int w = t >> 6, lane = t & 63, quad = lane >> 4, ln = lane & 15;
  const int m0 = blockIdx.x * 64;
  const int cy = blockIdx.y;                  // 0..14
  const int a = cy / 5;                       // 0=Q 1=K 2=V
  const int cc0 = (cy % 5) * 64;
  const int mt = (m0 >> 4) + w;
  const int ct0 = a * 20 + (cc0 >> 4);

  f32x4 acc[4] = {{0,0,0,0},{0,0,0,0},{0,0,0,0},{0,0,0,0}};
  for (int kc = 0; kc < 10; ++kc) {
    bf16x8 xf = ld_bf8(xbf + ((size_t)(mt * 10 + kc)) * 512 + lane * 8);
#pragma unroll
    for (int nt = 0; nt < 4; ++nt) {
      bf16x8 wf = ld_bf8(Wtf + ((size_t)((ct0 + nt) * 10 + kc)) * 512 + lane * 8);
      if (a < 2) acc[nt] = mfma16(wf, xf, acc[nt]);   // D[c=quad*4+r][m=ln]
      else       acc[nt] = mfma16(xf, wf, acc[nt]);   // D[m=quad*4+r][c=ln]
    }
  }
  if (a == 0) {
    const int m = m0 + w * 16 + ln;
#pragma unroll
    for (int nt = 0; nt < 4; ++nt) {
      int c = cc0 + nt * 16 + quad * 4;       // 4 consecutive d, no h-crossing
      int h = c / DH, d = c % DH;
      uint2 pk = pack4(acc[nt][0] * QSCALE, acc[nt][1] * QSCALE,
                       acc[nt][2] * QSCALE, acc[nt][3] * QSCALE);
      *(uint2*)&Qb[((size_t)h * NT + m) * 64 + d] = pk;
    }
  } else if (a == 1) {
    const int m = m0 + w * 16 + ln;
#pragma unroll
    for (int nt = 0; nt < 4; ++nt) {
      int c = cc0 + nt * 16 + quad * 4;
      int h = c / DH, d = c % DH;
      uint2 pk = pack4(acc[nt][0], acc[nt][1], acc[nt][2], acc[nt][3]);
      size_t base = ((size_t)h * 256 + (m >> 4)) * KFJB;
      size_t idx = (d < 32)
          ? base + (size_t)(d >> 3) * 128 + (size_t)(m & 15) * 8 + (d & 7)
          : base + 512 + (size_t)(m & 15) * 8 + (d - 32);
      *(uint2*)&Kf[idx] = pk;
    }
  } else {
    const int mb = m0 + w * 16 + quad * 4;    // 4 consecutive m
#pragma unroll
    for (int nt = 0; nt < 4; ++nt) {
      int c = cc0 + nt * 16 + ln;
      int h = c / DH, d = c % DH;
      uint2 pk = pack4(acc[nt][0], acc[nt][1], acc[nt][2], acc[nt][3]);
      size_t idx = ((((((size_t)(h * 64 + (mb >> 6)) * 3 + (d >> 4)) * 2 +
                       ((mb >> 5) & 1)) * 4 + ((mb >> 3) & 3)) * 16 + (d & 15))) * 8 +
                   (mb & 7);
      *(uint2*)&Vf[idx] = pk;
    }
  }
}

// ---------------- kernel 3: partitioned masked attention + CU-mix swizzle -------
// grid (32,8,KS). qt = (bx + 8*sp) & 31: co-resident blocks (flat +-256, same bx/h,
// differing sp) get qt spread {q,q+8,q+16,q+24} -> each CU holds a MIX of full and
// writer blocks (r15 showed 4-of-a-kind per CU erased the partition win).
__global__ __launch_bounds__(256, 4) void attn_kernel(
    const unsigned short* __restrict__ Qb, const unsigned short* __restrict__ Kf,
    const unsigned short* __restrict__ Vf, const unsigned char* __restrict__ sigb,
    const int* __restrict__ perm, const int* __restrict__ nqp,
    unsigned short* __restrict__ Opf, float* __restrict__ Lpart) {
  __shared__ __align__(16) unsigned short pt[4][32 * PSTR];   // per-wave P^T 17408 B
  const int t = threadIdx.x;
  const int w = t >> 6, lane = t & 63, quad = lane >> 4, ln = lane & 15;
  const int h = blockIdx.y, sp = blockIdx.z;
  const int qt = (blockIdx.x + 8 * sp) & 31;   // CU-mix swizzle (the r17 change)
  const int qrow = qt * 128 + w * 32;
  const int j0 = sp * 16;
  const int nq_pad = (nqp[0] + 127) & ~127;
  const bool writer = (qt * 128 >= nq_pad);   // block-uniform

  const unsigned short* Kfh = Kf + (size_t)h * 256 * KFJB;
  const unsigned short* Vfh = Vf + (size_t)h * 196608;   // 64jt * 3ot * 2c * 512
  unsigned short* ptw = pt[w];
  const uint4 z4 = {0, 0, 0, 0};
  const uint4 ones4 = {0x3F803F80u, 0x3F803F80u, 0x3F803F80u, 0x3F803F80u};
  const bf16x8 onesb = __builtin_bit_cast(bf16x8, ones4);
  const bool vone = (ln == 8);             // d=40 rows of the ot=2 V-frag -> 1.0

  bf16x8 qa[2][2];
  unsigned sqx4[2], uqx4[2];
  int morig[2];
  f32x4 o[3][2] = {{{0,0,0,0},{0,0,0,0}},{{0,0,0,0},{0,0,0,0}},{{0,0,0,0},{0,0,0,0}}};

#pragma unroll
  for (int tq = 0; tq < 2; ++tq) {
    int bp = qrow + tq * 16 + ln;
    int mo = perm[bp];
    morig[tq] = mo;
    if (!writer) {
      const unsigned short* Qp = Qb + ((size_t)h * NT + mo) * 64;
      qa[tq][0] = ld_bf8(Qp + quad * 8);                // k 0..31
      uint4 q1 = z4;                                    // k 32..39: quad0 real
      if (quad == 0) q1 = *(const uint4*)(Qp + 32);
      qa[tq][1] = __builtin_bit_cast(bf16x8, q1);
      unsigned s = sigb[mo];
      sqx4[tq] = s * 0x01010101u;
      uqx4[tq] = (s == 0u) ? 0xFFFFFFFFu : 0u;
      if (s == 0u) {               // boundary pad rows: logits 0 -> p = 1
        qa[tq][0] = __builtin_bit_cast(bf16x8, z4);
        qa[tq][1] = __builtin_bit_cast(bf16x8, z4);
      }
    }
  }

  for (int jt = j0; jt < j0 + 16; ++jt) {
    if (!writer) {
      // K fragments from compact Kf: 4 x 1KB + 4 x 256B (quad0) coalesced loads
      uint4 kfr0[4], kfr1[4];
#pragma unroll
      for (int nt = 0; nt < 4; ++nt) {
        const unsigned short* kb = Kfh + (size_t)(jt * 4 + nt) * KFJB;
        kfr0[nt] = *(const uint4*)(kb + lane * 8);
        kfr1[nt] = z4;
        if (lane < 16) kfr1[nt] = *(const uint4*)(kb + 512 + lane * 8);
      }
#pragma unroll
      for (int nt = 0; nt < 4; ++nt) {
        bf16x8 ka0 = __builtin_bit_cast(bf16x8, kfr0[nt]);
        bf16x8 ka1 = __builtin_bit_cast(bf16x8, kfr1[nt]);
        unsigned spj = *(const unsigned*)(sigb + jt * 64 + nt * 16 + quad * 4);
#pragma unroll
        for (int tq = 0; tq < 2; ++tq) {
          f32x4 acc = {0.f, 0.f, 0.f, 0.f};
          acc = mfma16(ka0, qa[tq][0], acc);    // S^T[j=nt*16+quad*4+r][m=ln]
          acc = mfma16(ka1, qa[tq][1], acc);
          unsigned m4 = (spj & sqx4[tq]) | uqx4[tq];   // byte r != 0 <=> unmasked
          unsigned u[4];
#pragma unroll
          for (int r = 0; r < 4; ++r) {
            unsigned mb = (m4 >> (8 * r)) & 255u;      // v_bfe
            float am = mb ? acc[r] : -3.0e38f;         // masked -> exp2 = 0
            u[r] = __builtin_bit_cast(unsigned, fexp2(am));
          }
          uint2 pk;                                    // truncate-to-bf16 pack
          pk.x = (u[0] >> 16) | (u[1] & 0xffff0000u);  // (j+0, j+1)
          pk.y = (u[2] >> 16) | (u[3] & 0xffff0000u);  // (j+2, j+3)
          *(uint2*)&ptw[(tq * 16 + ln) * PSTR + nt * 16 + quad * 4] = pk;  // b64
        }
      }
    }
    // V fragments (6 coalesced 1KB wave loads); ones-column d=40 in-register
    uint4 vfr[6];
#pragma unroll
    for (int ot = 0; ot < 3; ++ot)
#pragma unroll
      for (int c = 0; c < 2; ++c)
        vfr[ot * 2 + c] =
            *(const uint4*)(Vfh + ((size_t)((jt * 3 + ot) * 2 + c)) * 512 + lane * 8);
    if (vone) { vfr[4] = ones4; vfr[5] = ones4; }

    bf16x8 pb[2][2];
    if (!writer) {
      asm volatile("s_waitcnt lgkmcnt(0)" ::: "memory");   // wave-private P RAW
#pragma unroll
      for (int tq = 0; tq < 2; ++tq) {
        pb[tq][0] = ld_bf8(&ptw[(tq * 16 + ln) * PSTR + quad * 8]);
        pb[tq][1] = ld_bf8(&ptw[(tq * 16 + ln) * PSTR + 32 + quad * 8]);
      }
    } else {
      pb[0][0] = onesb; pb[0][1] = onesb; pb[1][0] = onesb; pb[1][1] = onesb;
    }
#pragma unroll
    for (int ot = 0; ot < 3; ++ot) {
      bf16x8 va0 = __builtin_bit_cast(bf16x8, vfr[ot * 2]);
      bf16x8 va1 = __builtin_bit_cast(bf16x8, vfr[ot * 2 + 1]);
#pragma unroll
      for (int tq = 0; tq < 2; ++tq) {
        o[ot][tq] = mfma16(va0, pb[tq][0], o[ot][tq]);   // O^T[d][m]
        o[ot][tq] = mfma16(va1, pb[tq][1], o[ot][tq]);
      }
    }
  }

  // epilogue: O^T d = ot*16+quad*4+r; scatter by original row; d=40 -> denominator
#pragma unroll
  for (int tq = 0; tq < 2; ++tq) {
    int m = morig[tq];
#pragma unroll
    for (int ot = 0; ot < 3; ++ot) {
      int d0 = ot * 16 + quad * 4;
      if (d0 < DH) {
        int c = h * DH + d0;                  // 4 consecutive c, no 8-crossing
        uint2 pk = pack4(o[ot][tq][0], o[ot][tq][1], o[ot][tq][2], o[ot][tq][3]);
        *(uint2*)&Opf[fmi(sp * 256 + (m >> 4), 10, c, m)] = pk;
      }
    }
    if (quad == 2)
      Lpart[sp * NT + m] = o[2][tq][0];       // MFMA-computed denominator
  }
}

// ---------------- kernel 4: out projection + split-K combine + bias ----------------
__global__ __launch_bounds__(256, 4) void out_gemm(
    const unsigned short* __restrict__ Opf, const float* __restrict__ Lpart,
    const unsigned short* __restrict__ Wtf, const float* __restrict__ bo,
    float* __restrict__ out) {
  const int t = threadIdx.x;
  const int w = t >> 6, lane = t & 63, quad = lane >> 4, ln = lane & 15;
  const int m0 = blockIdx.x * 64;
  const int cc0 = blockIdx.y * 64;
  const int mt = (m0 >> 4) + w;
  const int m = m0 + w * 16 + ln;
  const int ct0 = 60 + (cc0 >> 4);
  float ls = 0.f;
#pragma unroll
  for (int sp = 0; sp < KS; ++sp) ls += Lpart[sp * NT + m];
  const float inv = 1.f / ls;

  f32x4 acc[4] = {{0,0,0,0},{0,0,0,0},{0,0,0,0},{0,0,0,0}};
  for (int kc = 0; kc < 10; ++kc) {
    float s8[8] = {0, 0, 0, 0, 0, 0, 0, 0};
#pragma unroll
    for (int sp = 0; sp < KS; ++sp) {
      uint4 v = *(const uint4*)(Opf + ((size_t)((sp * 256 + mt) * 10 + kc)) * 512 +
                                lane * 8);
      unsigned vv[4] = {v.x, v.y, v.z, v.w};
#pragma unroll
      for (int j = 0; j < 4; ++j) {
        s8[2 * j]     += __builtin_bit_cast(float, vv[j] << 16);
        s8[2 * j + 1] += __builtin_bit_cast(float, vv[j] & 0xffff0000u);
      }
    }
    unsigned short af8[8];
#pragma unroll
    for (int j = 0; j < 8; ++j) af8[j] = f2b(s8[j] * inv);
    bf16x8 af = ld_bf8(af8);
#pragma unroll
    for (int nt = 0; nt < 4; ++nt) {
      bf16x8 wf = ld_bf8(Wtf + ((size_t)((ct0 + nt) * 10 + kc)) * 512 + lane * 8);
      acc[nt] = mfma16(wf, af, acc[nt]);      // D[c=quad*4+r][m=ln]
    }
  }
#pragma unroll
  for (int nt = 0; nt < 4; ++nt) {
    int c = cc0 + nt * 16 + quad * 4;
    float4 bv = *(const float4*)(bo + c);
    float4 ov;
    ov.x = acc[nt][0] + bv.x;
    ov.y = acc[nt][1] + bv.y;
    ov.z = acc[nt][2] + bv.z;
    ov.w = acc[nt][3] + bv.w;
    *(float4*)(out + (size_t)m * DM + c) = ov;
  }
}

// ---------------- launcher ----------------
extern "C" void kernel_launch(void* const* d_in, const int* in_sizes, int n_in,
                              void* d_out, int out_size, void* d_ws, size_t ws_size,
                              hipStream_t stream) {
  const float* x  = (const float*)d_in[0];
  const float* g  = (const float*)d_in[1];
  const float* Wq = (const float*)d_in[2];
  const float* Wk = (const float*)d_in[3];
  const float* Wv = (const float*)d_in[4];
  const float* Wo = (const float*)d_in[5];
  const float* bo = (const float*)d_in[6];
  float* out = (float*)d_out;

  char* ws = (char*)d_ws;
  const size_t SIG_OFF  = 0;                                        // 4 KB
  const size_t NQ_OFF   = 4096;                                     // 16 B
  const size_t PERM_OFF = 8192;                                     // 16 KB
  const size_t XBF_OFF  = 32768;
  const size_t WTF_OFF = XBF_OFF + (size_t)NT * DM * 2;             // +2.62 MB
  const size_t QB_OFF  = WTF_OFF + (size_t)1280 * DM * 2;           // +0.82 MB
  const size_t KF_OFF  = QB_OFF + (size_t)NH * NT * 64 * 2;         // +4.19 MB
  const size_t VF_OFF  = KF_OFF + (size_t)NH * 256 * KFJB * 2;      // +2.62 MB
  const size_t OPF_OFF = VF_OFF + (size_t)NH * 196608 * 2;          // +3.15 MB
  const size_t LP_OFF  = OPF_OFF + (size_t)KS * 256 * 10 * 512 * 2; // +10.49 MB
  unsigned char* sigb  = (unsigned char*)(ws + SIG_OFF);
  int* nqp             = (int*)(ws + NQ_OFF);
  int* perm            = (int*)(ws + PERM_OFF);
  unsigned short* xbf  = (unsigned short*)(ws + XBF_OFF);
  unsigned short* Wtf  = (unsigned short*)(ws + WTF_OFF);
  unsigned short* Qb   = (unsigned short*)(ws + QB_OFF);
  unsigned short* Kf   = (unsigned short*)(ws + KF_OFF);
  unsigned short* Vf   = (unsigned short*)(ws + VF_OFF);
  unsigned short* Opf  = (unsigned short*)(ws + OPF_OFF);
  float* Lpart         = (float*)(ws + LP_OFF);

  // No memset: Qb k40..63 garbage never read (quad-select); Vf d=40 ones
  // in-register; Vf d=41..47 garbage feeds only discarded lanes (no NaN).
  prep_kernel<<<229, 256, 0, stream>>>(x, g, Wq, Wk, Wv, Wo, xbf, sigb, Wtf,
                                       perm, nqp);
  qkv_gemm<<<dim3(64, 15), 256, 0, stream>>>(xbf, Wtf, Qb, Kf, Vf);
  attn_kernel<<<dim3(32, NH, KS), 256, 0, stream>>>(Qb, Kf, Vf, sigb, perm, nqp,
                                                    Opf, Lpart);
  out_gemm<<<dim3(64, 5), 256, 0, stream>>>(Opf, Lpart, Wtf, bo, out);
}

// Round 18
// 138.250 us; speedup vs baseline: 1.1394x; 1.0155x over previous
//
#include <hip/hip_runtime.h>
#include <hip/hip_bf16.h>
#include <stdint.h>

// Problem constants
#define NT 4096      // tokens
#define DM 320       // model dim
#define NH 8         // heads
#define DH 40        // head dim
#define KS 4         // split-K factor over the key dimension
#define QSCALE 0.22811013f  // (1/sqrt(40)) * log2(e): folded into Q so p = exp2(qk)
#define PSTR 68      // P-tile LDS row stride (ushorts): b64 8B-aligned, <=2-way banks
#define KFJB 640     // Kf shorts per 16-key block: 512 (k<32) + 128 (k=32..39, quad0)

typedef float f32x4 __attribute__((ext_vector_type(4)));
typedef __bf16 bf16x8 __attribute__((ext_vector_type(8)));

__device__ __forceinline__ unsigned short f2b(float f) {
  unsigned u = __builtin_bit_cast(unsigned, f);
  u += 0x7FFFu + ((u >> 16) & 1u);   // RNE
  return (unsigned short)(u >> 16);
}

__device__ __forceinline__ bf16x8 ld_bf8(const unsigned short* p) {
  uint4 v = *(const uint4*)p;        // 16B load
  return __builtin_bit_cast(bf16x8, v);
}

__device__ __forceinline__ f32x4 mfma16(bf16x8 a, bf16x8 b, f32x4 c) {
  return __builtin_amdgcn_mfma_f32_16x16x32_bf16(a, b, c, 0, 0, 0);
}

__device__ __forceinline__ float fexp2(float x) {
#if __has_builtin(__builtin_amdgcn_exp2f)
  return __builtin_amdgcn_exp2f(x);
#else
  float r; asm("v_exp_f32 %0, %1" : "=v"(r) : "v"(x)); return r;
#endif
}

__device__ __forceinline__ uint2 pack4(float a, float b, float c, float d) {
  uint2 pk;
  pk.x = (unsigned)f2b(a) | ((unsigned)f2b(b) << 16);
  pk.y = (unsigned)f2b(c) | ((unsigned)f2b(d) << 16);
  return pk;
}

// Fragment-major index: element (outer o in 16-tile `tile`, inner k of nk 32-tiles)
__device__ __forceinline__ size_t fmi(int tile, int nk, int k, int o) {
  return ((size_t)tile * nk + (k >> 5)) * 512 + (size_t)((k >> 3) & 3) * 128 +
         (size_t)(o & 15) * 8 + (k & 7);
}

// ---------------- kernel 1: prep (weights->Wtf | sig+partition | x->xbf) ---------
// block 100: signatures + stable partition (sig!=0 first) -> perm, invp, sgp, nq.
__global__ __launch_bounds__(256) void prep_kernel(
    const float* __restrict__ x, const float* __restrict__ g,
    const float* __restrict__ Wq, const float* __restrict__ Wk,
    const float* __restrict__ Wv, const float* __restrict__ Wo,
    unsigned short* __restrict__ xbf, unsigned char* __restrict__ sgp,
    unsigned short* __restrict__ Wtf, int* __restrict__ perm,
    int* __restrict__ invp, int* __restrict__ nqp) {
  const int b = blockIdx.x, t = threadIdx.x;
  if (b == 100) {                       // ---- signatures + partition
    __shared__ int cnt[256];
    unsigned char mys[16];
    int c1 = 0;
#pragma unroll
    for (int i = 0; i < 16; ++i) {
      int tok = t * 16 + i;
      unsigned s = 0;
      if (g[tok] != 0.f)          s |= 1u;
      if (g[NT + tok] != 0.f)     s |= 2u;
      if (g[2 * NT + tok] != 0.f) s |= 4u;
      mys[i] = (unsigned char)s;
      c1 += (s != 0u);
    }
    cnt[t] = c1;
    __syncthreads();
    for (int off = 1; off < 256; off <<= 1) {   // inclusive scan
      int v = (t >= off) ? cnt[t - off] : 0;
      __syncthreads();
      cnt[t] += v;
      __syncthreads();
    }
    const int nq = cnt[255];
    int p1 = cnt[t] - c1;                       // exclusive prefix of non-zero
    int p0 = nq + (t * 16 - p1);                // sig0 slots after all non-zero
#pragma unroll
    for (int i = 0; i < 16; ++i) {
      int tok = t * 16 + i;
      if (mys[i] != 0) { perm[p1] = tok; invp[tok] = p1; sgp[p1] = mys[i]; p1++; }
      else             { perm[p0] = tok; invp[tok] = p0; sgp[p0] = 0;      p0++; }
    }
    if (t == 0) nqp[0] = nq;
    return;
  }
  if (b > 100) {                        // ---- x -> bf16 frag-major (fat blocks)
    int base = (b - 101) * 2560;        // 128 blocks x 2560 float4
#pragma unroll
    for (int j = 0; j < 10; ++j) {
      int i = (base + j * 256 + t) * 4;
      int m = i / DM, k = i % DM;
      float4 v = *(const float4*)(x + i);
      ushort4 u;
      u.x = f2b(v.x); u.y = f2b(v.y); u.z = f2b(v.z); u.w = f2b(v.w);
      *(ushort4*)(xbf + fmi(m >> 4, 10, k, m)) = u;
    }
    return;
  }
  // ---- weights -> bf16 transposed frag-major
  __shared__ __align__(16) unsigned short lt[64 * 72];
  int kx = b % 5, cy = b / 5;           // kx: k-tile, cy: c-tile over 4 mats
  int cm = cy % 5;
  const float* src;
  int rowbase;
  if (cy < 5)       { src = Wq; rowbase = cm * 64; }
  else if (cy < 10) { src = Wk; rowbase = 320 + cm * 64; }
  else if (cy < 15) { src = Wv; rowbase = 640 + cm * 64; }
  else              { src = Wo; rowbase = 960 + cm * 64; }
  const int c0 = cm * 64;
  const int k0 = kx * 64;
#pragma unroll
  for (int i = 0; i < 4; ++i) {         // read 64k x 64c fp32, transpose to LDS
    int kr = (t >> 4) + i * 16, cc = (t & 15) * 4;
    float4 w4 = *(const float4*)&src[(size_t)(k0 + kr) * DM + c0 + cc];
    lt[(cc + 0) * 72 + kr] = f2b(w4.x);
    lt[(cc + 1) * 72 + kr] = f2b(w4.y);
    lt[(cc + 2) * 72 + kr] = f2b(w4.z);
    lt[(cc + 3) * 72 + kr] = f2b(w4.w);
  }
  __syncthreads();
#pragma unroll
  for (int i = 0; i < 2; ++i) {         // scatter to frag-major (8-short chunks)
    int idx = t + i * 256, cl = idx >> 3, ch = idx & 7;
    int c = rowbase + cl, k = k0 + ch * 8;
    *(uint4*)&Wtf[fmi(c >> 4, 10, k, c)] = *(const uint4*)&lt[cl * 72 + ch * 8];
  }
}

// ---------------- kernel 2: fused QKV projection (token-permuted outputs) --------
// Q/K/V all stored at bucketed positions bp = invp[m] (sig!=0 tokens first) so
// attn can SKIP the sig0 key tiles. Q: row layout Qb[h][bp][64]. K: compact
// frag-major at bp. V: frag-major at bp (scalar scatter: 4 bp's are unrelated).
__global__ __launch_bounds__(256, 4) void qkv_gemm(
    const unsigned short* __restrict__ xbf, const unsigned short* __restrict__ Wtf,
    const int* __restrict__ invp,
    unsigned short* __restrict__ Qb, unsigned short* __restrict__ Kf,
    unsigned short* __restrict__ Vf) {
  const int t = threadIdx.x;
  const int w = t >> 6, lane = t & 63, quad = lane >> 4, ln = lane & 15;
  const int m0 = blockIdx.x * 64;
  const int cy = blockIdx.y;                  // 0..14
  const int a = cy / 5;                       // 0=Q 1=K 2=V
  const int cc0 = (cy % 5) * 64;
  const int mt = (m0 >> 4) + w;
  const int ct0 = a * 20 + (cc0 >> 4);

  f32x4 acc[4] = {{0,0,0,0},{0,0,0,0},{0,0,0,0},{0,0,0,0}};
  for (int kc = 0; kc < 10; ++kc) {
    bf16x8 xf = ld_bf8(xbf + ((size_t)(mt * 10 + kc)) * 512 + lane * 8);
#pragma unroll
    for (int nt = 0; nt < 4; ++nt) {
      bf16x8 wf = ld_bf8(Wtf + ((size_t)((ct0 + nt) * 10 + kc)) * 512 + lane * 8);
      if (a < 2) acc[nt] = mfma16(wf, xf, acc[nt]);   // D[c=quad*4+r][m=ln]
      else       acc[nt] = mfma16(xf, wf, acc[nt]);   // D[m=quad*4+r][c=ln]
    }
  }
  if (a == 0) {
    const int bp = invp[m0 + w * 16 + ln];
#pragma unroll
    for (int nt = 0; nt < 4; ++nt) {
      int c = cc0 + nt * 16 + quad * 4;       // 4 consecutive d, no h-crossing
      int h = c / DH, d = c % DH;
      uint2 pk = pack4(acc[nt][0] * QSCALE, acc[nt][1] * QSCALE,
                       acc[nt][2] * QSCALE, acc[nt][3] * QSCALE);
      *(uint2*)&Qb[((size_t)h * NT + bp) * 64 + d] = pk;
    }
  } else if (a == 1) {
    const int bp = invp[m0 + w * 16 + ln];
#pragma unroll
    for (int nt = 0; nt < 4; ++nt) {
      int c = cc0 + nt * 16 + quad * 4;
      int h = c / DH, d = c % DH;
      uint2 pk = pack4(acc[nt][0], acc[nt][1], acc[nt][2], acc[nt][3]);
      size_t base = ((size_t)h * 256 + (bp >> 4)) * KFJB;
      size_t idx = (d < 32)
          ? base + (size_t)(d >> 3) * 128 + (size_t)(bp & 15) * 8 + (d & 7)
          : base + 512 + (size_t)(bp & 15) * 8 + (d - 32);
      *(uint2*)&Kf[idx] = pk;
    }
  } else {
    const int mb = m0 + w * 16 + quad * 4;    // 4 consecutive m -> scattered bp
    int bpr[4];
#pragma unroll
    for (int r = 0; r < 4; ++r) bpr[r] = invp[mb + r];
#pragma unroll
    for (int nt = 0; nt < 4; ++nt) {
      int c = cc0 + nt * 16 + ln;
      int h = c / DH, d = c % DH;
#pragma unroll
      for (int r = 0; r < 4; ++r) {
        int bp = bpr[r];
        size_t idx = ((((((size_t)(h * 64 + (bp >> 6)) * 3 + (d >> 4)) * 2 +
                         ((bp >> 5) & 1)) * 4 + ((bp >> 3) & 3)) * 16 + (d & 15))) * 8 +
                     (bp & 7);
        Vf[idx] = f2b(acc[nt][r]);
      }
    }
  }
}

// ---------------- kernel 3: partitioned attention with KEY-TILE SKIP ------------
// grid (32,8,KS), qt swizzled for CU mix. Keys permuted (sig!=0 first):
//  - full-fast blocks ((qt+1)*128 <= nq): iterate only nkt = ceil(nq/64) key tiles
//    (sig0 keys contribute p=0 — skipped exactly);
//  - mixed block (contains boundary uniform rows): all 64 tiles (uq rows need
//    every key; full rows mask sig0 keys to 0 -> unchanged);
//  - writer blocks (all rows uniform): all 64 tiles, P = ones, no QK/exp/LDS.
// Splits are strided: jt = sp, sp+KS, ... (any tile partition is valid).
__global__ __launch_bounds__(256, 4) void attn_kernel(
    const unsigned short* __restrict__ Qb, const unsigned short* __restrict__ Kf,
    const unsigned short* __restrict__ Vf, const unsigned char* __restrict__ sgp,
    const int* __restrict__ perm, const int* __restrict__ nqp,
    unsigned short* __restrict__ Opf, float* __restrict__ Lpart) {
  __shared__ __align__(16) unsigned short pt[4][32 * PSTR];   // per-wave P^T 17408 B
  const int t = threadIdx.x;
  const int w = t >> 6, lane = t & 63, quad = lane >> 4, ln = lane & 15;
  const int h = blockIdx.y, sp = blockIdx.z;
  const int qt = (blockIdx.x + 8 * sp) & 31;   // CU-mix swizzle (r17)
  const int qrow = qt * 128 + w * 32;
  const int nq = nqp[0];
  const int nkt = (nq + 63) >> 6;
  const int nq_pad = (nq + 127) & ~127;
  const bool writer = (qt * 128 >= nq_pad);    // block-uniform
  const int jt_end = (!writer && (qt + 1) * 128 <= nq) ? nkt : 64;

  const unsigned short* Kfh = Kf + (size_t)h * 256 * KFJB;
  const unsigned short* Vfh = Vf + (size_t)h * 196608;   // 64jt * 3ot * 2c * 512
  unsigned short* ptw = pt[w];
  const uint4 z4 = {0, 0, 0, 0};
  const uint4 ones4 = {0x3F803F80u, 0x3F803F80u, 0x3F803F80u, 0x3F803F80u};
  const bf16x8 onesb = __builtin_bit_cast(bf16x8, ones4);
  const bool vone = (ln == 8);             // d=40 rows of the ot=2 V-frag -> 1.0

  bf16x8 qa[2][2];
  unsigned sqx4[2], uqx4[2];
  int morig[2];
  f32x4 o[3][2] = {{{0,0,0,0},{0,0,0,0}},{{0,0,0,0},{0,0,0,0}},{{0,0,0,0},{0,0,0,0}}};

#pragma unroll
  for (int tq = 0; tq < 2; ++tq) {
    int bp = qrow + tq * 16 + ln;
    morig[tq] = perm[bp];
    if (!writer) {
      const unsigned short* Qp = Qb + ((size_t)h * NT + bp) * 64;
      qa[tq][0] = ld_bf8(Qp + quad * 8);                // k 0..31
      uint4 q1 = z4;                                    // k 32..39: quad0 real
      if (quad == 0) q1 = *(const uint4*)(Qp + 32);
      qa[tq][1] = __builtin_bit_cast(bf16x8, q1);
      unsigned s = sgp[bp];
      sqx4[tq] = s * 0x01010101u;
      uqx4[tq] = (s == 0u) ? 0xFFFFFFFFu : 0u;
      if (s == 0u) {               // boundary uniform rows: logits 0 -> p = 1
        qa[tq][0] = __builtin_bit_cast(bf16x8, z4);
        qa[tq][1] = __builtin_bit_cast(bf16x8, z4);
      }
    }
  }

  for (int jt = sp; jt < jt_end; jt += KS) {
    if (!writer) {
      // K fragments from compact Kf: 4 x 1KB + 4 x 256B (quad0) coalesced loads
      uint4 kfr0[4], kfr1[4];
#pragma unroll
      for (int nt = 0; nt < 4; ++nt) {
        const unsigned short* kb = Kfh + (size_t)(jt * 4 + nt) * KFJB;
        kfr0[nt] = *(const uint4*)(kb + lane * 8);
        kfr1[nt] = z4;
        if (lane < 16) kfr1[nt] = *(const uint4*)(kb + 512 + lane * 8);
      }
#pragma unroll
      for (int nt = 0; nt < 4; ++nt) {
        bf16x8 ka0 = __builtin_bit_cast(bf16x8, kfr0[nt]);
        bf16x8 ka1 = __builtin_bit_cast(bf16x8, kfr1[nt]);
        unsigned spj = *(const unsigned*)(sgp + jt * 64 + nt * 16 + quad * 4);
#pragma unroll
        for (int tq = 0; tq < 2; ++tq) {
          f32x4 acc = {0.f, 0.f, 0.f, 0.f};
          acc = mfma16(ka0, qa[tq][0], acc);    // S^T[j=nt*16+quad*4+r][m=ln]
          acc = mfma16(ka1, qa[tq][1], acc);
          unsigned m4 = (spj & sqx4[tq]) | uqx4[tq];   // byte r != 0 <=> unmasked
          unsigned u[4];
#pragma unroll
          for (int r = 0; r < 4; ++r) {
            unsigned mb = (m4 >> (8 * r)) & 255u;      // v_bfe
            float am = mb ? acc[r] : -3.0e38f;         // masked -> exp2 = 0
            u[r] = __builtin_bit_cast(unsigned, fexp2(am));
          }
          uint2 pk;                                    // truncate-to-bf16 pack
          pk.x = (u[0] >> 16) | (u[1] & 0xffff0000u);  // (j+0, j+1)
          pk.y = (u[2] >> 16) | (u[3] & 0xffff0000u);  // (j+2, j+3)
          *(uint2*)&ptw[(tq * 16 + ln) * PSTR + nt * 16 + quad * 4] = pk;  // b64
        }
      }
    }
    // V fragments (6 coalesced 1KB wave loads); ones-column d=40 in-register
    uint4 vfr[6];
#pragma unroll
    for (int ot = 0; ot < 3; ++ot)
#pragma unroll
      for (int c = 0; c < 2; ++c)
        vfr[ot * 2 + c] =
            *(const uint4*)(Vfh + ((size_t)((jt * 3 + ot) * 2 + c)) * 512 + lane * 8);
    if (vone) { vfr[4] = ones4; vfr[5] = ones4; }

    bf16x8 pb[2][2];
    if (!writer) {
      asm volatile("s_waitcnt lgkmcnt(0)" ::: "memory");   // wave-private P RAW
#pragma unroll
      for (int tq = 0; tq < 2; ++tq) {
        pb[tq][0] = ld_bf8(&ptw[(tq * 16 + ln) * PSTR + quad * 8]);
        pb[tq][1] = ld_bf8(&ptw[(tq * 16 + ln) * PSTR + 32 + quad * 8]);
      }
    } else {
      pb[0][0] = onesb; pb[0][1] = onesb; pb[1][0] = onesb; pb[1][1] = onesb;
    }
#pragma unroll
    for (int ot = 0; ot < 3; ++ot) {
      bf16x8 va0 = __builtin_bit_cast(bf16x8, vfr[ot * 2]);
      bf16x8 va1 = __builtin_bit_cast(bf16x8, vfr[ot * 2 + 1]);
#pragma unroll
      for (int tq = 0; tq < 2; ++tq) {
        o[ot][tq] = mfma16(va0, pb[tq][0], o[ot][tq]);   // O^T[d][m]
        o[ot][tq] = mfma16(va1, pb[tq][1], o[ot][tq]);
      }
    }
  }

  // epilogue: O^T d = ot*16+quad*4+r; scatter by original row; d=40 -> denominator
#pragma unroll
  for (int tq = 0; tq < 2; ++tq) {
    int m = morig[tq];
#pragma unroll
    for (int ot = 0; ot < 3; ++ot) {
      int d0 = ot * 16 + quad * 4;
      if (d0 < DH) {
        int c = h * DH + d0;                  // 4 consecutive c, no 8-crossing
        uint2 pk = pack4(o[ot][tq][0], o[ot][tq][1], o[ot][tq][2], o[ot][tq][3]);
        *(uint2*)&Opf[fmi(sp * 256 + (m >> 4), 10, c, m)] = pk;
      }
    }
    if (quad == 2)
      Lpart[sp * NT + m] = o[2][tq][0];       // MFMA-computed denominator
  }
}

// ---------------- kernel 4: out projection + split-K combine + bias ----------------
__global__ __launch_bounds__(256, 4) void out_gemm(
    const unsigned short* __restrict__ Opf, const float* __restrict__ Lpart,
    const unsigned short* __restrict__ Wtf, const float* __restrict__ bo,
    float* __restrict__ out) {
  const int t = threadIdx.x;
  const int w = t >> 6, lane = t & 63, quad = lane >> 4, ln = lane & 15;
  const int m0 = blockIdx.x * 64;
  const int cc0 = blockIdx.y * 64;
  const int mt = (m0 >> 4) + w;
  const int m = m0 + w * 16 + ln;
  const int ct0 = 60 + (cc0 >> 4);
  float ls = 0.f;
#pragma unroll
  for (int sp = 0; sp < KS; ++sp) ls += Lpart[sp * NT + m];
  const float inv = 1.f / ls;

  f32x4 acc[4] = {{0,0,0,0},{0,0,0,0},{0,0,0,0},{0,0,0,0}};
  for (int kc = 0; kc < 10; ++kc) {
    float s8[8] = {0, 0, 0, 0, 0, 0, 0, 0};
#pragma unroll
    for (int sp = 0; sp < KS; ++sp) {
      uint4 v = *(const uint4*)(Opf + ((size_t)((sp * 256 + mt) * 10 + kc)) * 512 +
                                lane * 8);
      unsigned vv[4] = {v.x, v.y, v.z, v.w};
#pragma unroll
      for (int j = 0; j < 4; ++j) {
        s8[2 * j]     += __builtin_bit_cast(float, vv[j] << 16);
        s8[2 * j + 1] += __builtin_bit_cast(float, vv[j] & 0xffff0000u);
      }
    }
    unsigned short af8[8];
#pragma unroll
    for (int j = 0; j < 8; ++j) af8[j] = f2b(s8[j] * inv);
    bf16x8 af = ld_bf8(af8);
#pragma unroll
    for (int nt = 0; nt < 4; ++nt) {
      bf16x8 wf = ld_bf8(Wtf + ((size_t)((ct0 + nt) * 10 + kc)) * 512 + lane * 8);
      acc[nt] = mfma16(wf, af, acc[nt]);      // D[c=quad*4+r][m=ln]
    }
  }
#pragma unroll
  for (int nt = 0; nt < 4; ++nt) {
    int c = cc0 + nt * 16 + quad * 4;
    float4 bv = *(const float4*)(bo + c);
    float4 ov;
    ov.x = acc[nt][0] + bv.x;
    ov.y = acc[nt][1] + bv.y;
    ov.z = acc[nt][2] + bv.z;
    ov.w = acc[nt][3] + bv.w;
    *(float4*)(out + (size_t)m * DM + c) = ov;
  }
}

// ---------------- launcher ----------------
extern "C" void kernel_launch(void* const* d_in, const int* in_sizes, int n_in,
                              void* d_out, int out_size, void* d_ws, size_t ws_size,
                              hipStream_t stream) {
  const float* x  = (const float*)d_in[0];
  const float* g  = (const float*)d_in[1];
  const float* Wq = (const float*)d_in[2];
  const float* Wk = (const float*)d_in[3];
  const float* Wv = (const float*)d_in[4];
  const float* Wo = (const float*)d_in[5];
  const float* bo = (const float*)d_in[6];
  float* out = (float*)d_out;

  char* ws = (char*)d_ws;
  const size_t SGP_OFF  = 0;                                        // 4 KB
  const size_t NQ_OFF   = 4096;                                     // 16 B
  const size_t PERM_OFF = 8192;                                     // 16 KB
  const size_t INV_OFF  = 24576;                                    // 16 KB
  const size_t XBF_OFF  = 40960;
  const size_t WTF_OFF = XBF_OFF + (size_t)NT * DM * 2;             // +2.62 MB
  const size_t QB_OFF  = WTF_OFF + (size_t)1280 * DM * 2;           // +0.82 MB
  const size_t KF_OFF  = QB_OFF + (size_t)NH * NT * 64 * 2;         // +4.19 MB
  const size_t VF_OFF  = KF_OFF + (size_t)NH * 256 * KFJB * 2;      // +2.62 MB
  const size_t OPF_OFF = VF_OFF + (size_t)NH * 196608 * 2;          // +3.15 MB
  const size_t LP_OFF  = OPF_OFF + (size_t)KS * 256 * 10 * 512 * 2; // +10.49 MB
  unsigned char* sgp   = (unsigned char*)(ws + SGP_OFF);
  int* nqp             = (int*)(ws + NQ_OFF);
  int* perm            = (int*)(ws + PERM_OFF);
  int* invp            = (int*)(ws + INV_OFF);
  unsigned short* xbf  = (unsigned short*)(ws + XBF_OFF);
  unsigned short* Wtf  = (unsigned short*)(ws + WTF_OFF);
  unsigned short* Qb   = (unsigned short*)(ws + QB_OFF);
  unsigned short* Kf   = (unsigned short*)(ws + KF_OFF);
  unsigned short* Vf   = (unsigned short*)(ws + VF_OFF);
  unsigned short* Opf  = (unsigned short*)(ws + OPF_OFF);
  float* Lpart         = (float*)(ws + LP_OFF);

  // No memset: Qb k40..63 garbage never read (quad-select); Vf d=40 ones
  // in-register; Vf d=41..47 garbage feeds only discarded lanes (no NaN).
  prep_kernel<<<229, 256, 0, stream>>>(x, g, Wq, Wk, Wv, Wo, xbf, sgp, Wtf,
                                       perm, invp, nqp);
  qkv_gemm<<<dim3(64, 15), 256, 0, stream>>>(xbf, Wtf, invp, Qb, Kf, Vf);
  attn_kernel<<<dim3(32, NH, KS), 256, 0, stream>>>(Qb, Kf, Vf, sgp, perm, nqp,
                                                    Opf, Lpart);
  out_gemm<<<dim3(64, 5), 256, 0, stream>>>(Opf, Lpart, Wtf, bo, out);
}